// Round 1
// baseline (997.211 us; speedup 1.0000x reference)
//
#include <hip/hip_runtime.h>

#define N_ROWS 262144
#define NF 512
#define ND 8
#define F4 128            // float4 per row
#define EPSV 1e-5f

#define G1 256
#define B1 512
#define ROWS_PER_B1 (N_ROWS / G1)    // 1024
#define PSTRIDE 8448                  // floats per partial group (8200 used, padded)
#define NG2 16

#define G3 1024
#define B3 512
#define ROWS_PER_B3 (N_ROWS / G3)    // 256

// Accumulate one float4 into the (compile-time) domain-D register accumulators.
#define ACC1(D, V)                                              \
    sum[D][0] += (V).x; sq[D][0] = fmaf((V).x, (V).x, sq[D][0]); \
    sum[D][1] += (V).y; sq[D][1] = fmaf((V).y, (V).y, sq[D][1]); \
    sum[D][2] += (V).z; sq[D][2] = fmaf((V).z, (V).z, sq[D][2]); \
    sum[D][3] += (V).w; sq[D][3] = fmaf((V).w, (V).w, sq[D][3]); \
    cnt[D] += cinc;

// dom is wave-uniform (readfirstlane) -> scalar branch, no divergence.
#define ACCUM(DD, V) switch (DD) {            \
    case 0: { ACC1(0, V) } break;             \
    case 1: { ACC1(1, V) } break;             \
    case 2: { ACC1(2, V) } break;             \
    case 3: { ACC1(3, V) } break;             \
    case 4: { ACC1(4, V) } break;             \
    case 5: { ACC1(5, V) } break;             \
    case 6: { ACC1(6, V) } break;             \
    default: { ACC1(7, V) } break; }

// ---------------- kernel 1: per-block partial sums (no atomics) --------------
__global__ __launch_bounds__(B1, 2) void k1_partial(
    const float* __restrict__ x, const int* __restrict__ y,
    float* __restrict__ part /* d_out used as scratch */) {
  __shared__ float sSum[4][ND][F4];
  __shared__ float sSq[4][ND][F4];
  __shared__ float sCnt[ND];

  float sum[ND][4];
  float sq[ND][4];
  float cnt[ND];
#pragma unroll
  for (int d = 0; d < ND; ++d) {
    cnt[d] = 0.0f;
#pragma unroll
    for (int j = 0; j < 4; ++j) { sum[d][j] = 0.0f; sq[d][j] = 0.0f; }
  }

  const int tid = threadIdx.x;
  const int f4 = tid & (F4 - 1);
  const int rg = tid >> 7;               // 0..3
  const float cinc = (f4 == 0) ? 1.0f : 0.0f;  // count each row exactly once
  const float4* __restrict__ x4 = (const float4*)x;
  const int rowBase = blockIdx.x * ROWS_PER_B1;

  for (int r0 = 0; r0 < ROWS_PER_B1; r0 += 16) {
    const int r = rowBase + r0 + rg;
    // issue all 4 row loads first (ILP: 4 outstanding dwordx4 per thread)
    float4 v0 = x4[(size_t)(r +  0) * F4 + f4];
    float4 v1 = x4[(size_t)(r +  4) * F4 + f4];
    float4 v2 = x4[(size_t)(r +  8) * F4 + f4];
    float4 v3 = x4[(size_t)(r + 12) * F4 + f4];
    const int d0 = __builtin_amdgcn_readfirstlane(y[r +  0]);
    const int d1 = __builtin_amdgcn_readfirstlane(y[r +  4]);
    const int d2 = __builtin_amdgcn_readfirstlane(y[r +  8]);
    const int d3 = __builtin_amdgcn_readfirstlane(y[r + 12]);
    ACCUM(d0, v0)
    ACCUM(d1, v1)
    ACCUM(d2, v2)
    ACCUM(d3, v3)
  }

  // 4-phase LDS merge across rg groups (cross-wave, so LDS is required)
  for (int p = 0; p < 4; ++p) {
    if (rg == p) {
#pragma unroll
      for (int d = 0; d < ND; ++d) {
#pragma unroll
        for (int j = 0; j < 4; ++j) {
          if (p == 0) { sSum[j][d][f4] = sum[d][j]; sSq[j][d][f4] = sq[d][j]; }
          else        { sSum[j][d][f4] += sum[d][j]; sSq[j][d][f4] += sq[d][j]; }
        }
        if (f4 == 0) {
          if (p == 0) sCnt[d] = cnt[d]; else sCnt[d] += cnt[d];
        }
      }
    }
    __syncthreads();
  }

  // coalesced flush: [0,4096) sums, [4096,8192) sumsq, [8192,8200) counts
  float* __restrict__ pb = part + (size_t)blockIdx.x * PSTRIDE;
  for (int i = tid; i < 8200; i += B1) {
    float v;
    if (i < 4096) {
      const int d = i >> 9, f = i & 511;
      v = sSum[f & 3][d][f >> 2];
    } else if (i < 8192) {
      const int k = i - 4096;
      const int d = k >> 9, f = k & 511;
      v = sSq[f & 3][d][f >> 2];
    } else {
      v = sCnt[i - 8192];
    }
    pb[i] = v;
  }
}

// ---------------- kernel 1b: reduce 256 partials -> 16 ----------------------
__global__ void k1b_reduce(const float* __restrict__ part, float* __restrict__ p2) {
  const int i = blockIdx.x * 256 + threadIdx.x;
  if (i >= 8200) return;
  const int c = blockIdx.y;  // 0..15
  const float* __restrict__ p = part + (size_t)c * 16 * PSTRIDE + i;
  float a0 = 0.f, a1 = 0.f, a2 = 0.f, a3 = 0.f;
#pragma unroll
  for (int g = 0; g < 16; g += 4) {
    a0 += p[(size_t)(g + 0) * PSTRIDE];
    a1 += p[(size_t)(g + 1) * PSTRIDE];
    a2 += p[(size_t)(g + 2) * PSTRIDE];
    a3 += p[(size_t)(g + 3) * PSTRIDE];
  }
  p2[(size_t)c * PSTRIDE + i] = (a0 + a1) + (a2 + a3);
}

// ---------------- kernel 2: finalize stats -> scale/shift -------------------
__global__ void k2_finalize(const float* __restrict__ p2,
                            const float* __restrict__ gamma,
                            const float* __restrict__ beta,
                            float* __restrict__ ss /* ws: scale[4096], shift[4096] */) {
  const int i = blockIdx.x * 256 + threadIdx.x;  // 0..4095 (d*512 + f)
  const int d = i >> 9;
  float s = 0.f, q = 0.f, c = 0.f;
#pragma unroll
  for (int cc = 0; cc < NG2; ++cc) {
    const float* __restrict__ p = p2 + (size_t)cc * PSTRIDE;
    s += p[i];
    q += p[4096 + i];
    c += p[8192 + d];
  }
  const float safe = fmaxf(c, 1.0f);
  const float mean = s / safe;
  const float var = q / safe - mean * mean;
  const bool ub = c > 1.0f;                 // count==1 -> eval mode (mean 0, var 1)
  const float mean_e = ub ? mean : 0.0f;
  const float var_e = ub ? var : 1.0f;
  const float inv = rsqrtf(var_e + EPSV);
  float scale = gamma[i] * inv;
  float shift = beta[i] - scale * mean_e;
  if (!(c > 0.0f)) { scale = 0.0f; shift = 0.0f; }  // count==0 -> output zeros
  ss[i] = scale;
  ss[4096 + i] = shift;
}

// ---------------- kernel 3: normalize ---------------------------------------
__global__ __launch_bounds__(B3) void k3_normalize(
    const float* __restrict__ x, const int* __restrict__ y,
    const float* __restrict__ ss, float* __restrict__ out) {
  const int tid = threadIdx.x;
  const int f4 = tid & (F4 - 1);
  const int rg = tid >> 7;  // 0..3
  const float4* __restrict__ x4 = (const float4*)x;
  const float4* __restrict__ s4 = (const float4*)ss;            // scale
  const float4* __restrict__ t4 = (const float4*)(ss + 4096);   // shift
  float4* __restrict__ o4 = (float4*)out;
  const int rowBase = blockIdx.x * ROWS_PER_B3;

  for (int r0 = 0; r0 < ROWS_PER_B3; r0 += 8) {
    const int ra = rowBase + r0 + rg;
    const int rb = ra + 4;
    float4 va = x4[(size_t)ra * F4 + f4];
    float4 vb = x4[(size_t)rb * F4 + f4];
    const int da = y[ra];
    const int db = y[rb];
    float4 sa = s4[da * F4 + f4];
    float4 ta = t4[da * F4 + f4];
    float4 sb = s4[db * F4 + f4];
    float4 tb = t4[db * F4 + f4];
    float4 oa, ob;
    oa.x = fmaf(sa.x, va.x, ta.x);
    oa.y = fmaf(sa.y, va.y, ta.y);
    oa.z = fmaf(sa.z, va.z, ta.z);
    oa.w = fmaf(sa.w, va.w, ta.w);
    ob.x = fmaf(sb.x, vb.x, tb.x);
    ob.y = fmaf(sb.y, vb.y, tb.y);
    ob.z = fmaf(sb.z, vb.z, tb.z);
    ob.w = fmaf(sb.w, vb.w, tb.w);
    o4[(size_t)ra * F4 + f4] = oa;
    o4[(size_t)rb * F4 + f4] = ob;
  }
}

extern "C" void kernel_launch(void* const* d_in, const int* in_sizes, int n_in,
                              void* d_out, int out_size, void* d_ws, size_t ws_size,
                              hipStream_t stream) {
  const float* x     = (const float*)d_in[0];
  const int*   y     = (const int*)d_in[1];
  const float* gamma = (const float*)d_in[2];
  const float* beta  = (const float*)d_in[3];
  float* out = (float*)d_out;
  float* ws  = (float*)d_ws;  // needs only 8192 floats (32 KB)

  // d_out doubles as scratch for partials; k3 overwrites all of it afterwards.
  float* p1 = out;                              // 256 * 8448 floats (~8.6 MB)
  float* p2 = out + (size_t)G1 * PSTRIDE;       // 16 * 8448 floats

  k1_partial<<<G1, B1, 0, stream>>>(x, y, p1);
  k1b_reduce<<<dim3(33, NG2), 256, 0, stream>>>(p1, p2);
  k2_finalize<<<16, 256, 0, stream>>>(p2, gamma, beta, ws);
  k3_normalize<<<G3, B3, 0, stream>>>(x, y, ws, out);
}